// Round 7
// baseline (121.696 us; speedup 1.0000x reference)
//
#include <hip/hip_runtime.h>
#include <math.h>

#define NB 256     // N nodes
#define CH 64      // C input features
#define OUTF 64    // O output features
#define GK 8       // GRID_SIZE + SPLINE_ORDER
#define UIN 128    // update-KAN input dim (C + O)

// workspace layout (float offsets)
#define WS_MSG 0            // 512*64       = 32768
#define WS_PEXP 32768       // 2*256*256    = 131072
#define WS_PSUM 163840      // 2*256*4      = 2048
// total 165888 floats = 648 KB

__device__ __forceinline__ float silu(float v) {
    return v * __builtin_amdgcn_rcpf(1.0f + __expf(-v));
}

// Uniform cubic B-spline, knots t(m)=0.4m-2.2. Interval d=floor((r+2.2)*2.5);
// bases m=d-3..d nonzero; out-of-grid -> d=11 (zero rows in tables).
__device__ __forceinline__ void spline4(float r, int& d, float4& v) {
    float p = (r + 2.2f) * 2.5f;
    float fd = floorf(p);
    d = (int)fd;
    float u = p - fd;
    if ((unsigned)d > 10u) d = 11;
    float um = 1.0f - u;
    float u2 = u * u, u3 = u2 * u;
    const float k6 = 1.0f / 6.0f;
    v.x = um * um * um * k6;
    v.y = (3.0f * u3 - 6.0f * u2 + 4.0f) * k6;
    v.z = (-3.0f * u3 + 3.0f * u2 + 3.0f * u + 1.0f) * k6;
    v.w = u3 * k6;
}

// write channel c's 9 basis values into column c of Bt[9][W] (g-major)
template <int W>
__device__ __forceinline__ void basis_col(float v, float (*Bt)[W], int c) {
    int d; float4 vv; spline4(v, d, vv);
#pragma unroll
    for (int g = 0; g < 8; ++g) Bt[g][c] = 0.0f;
#pragma unroll
    for (int k = 0; k < 4; ++k) {
        int m = d - 3 + k;
        if ((unsigned)m < 8u) Bt[m][c] = ((const float*)&vv)[k];
    }
    Bt[8][c] = silu(v);
}

// K1: blocks 0..511 = msg rows; blocks 512..2559 = energy quarter-rows.
__global__ __launch_bounds__(256, 4) void k1_kernel(
    const float* __restrict__ x, const int* __restrict__ adj,
    const float* __restrict__ fwb, const float* __restrict__ fws,
    const float* __restrict__ fwsc,
    const float* __restrict__ mwb, const float* __restrict__ mws,
    const float* __restrict__ mwsc,
    float* __restrict__ ws) {
    const int blk = blockIdx.x, tid = threadIdx.x;
    const int lane = tid & 63, w = tid >> 6;

    __shared__ union {
        float mBt[9][CH];                       // M-block basis
        struct {
            float tile[CH][65];                 // xj tile, [c][j], padded
            __align__(16) float4 cpad[CH][12];  // per-interval cubic coefs
            float2 xisf[CH];                    // {xi[c], fwb[c]}
            float part[4][64];
        } e;
    } sm;

    if (blk < 512) {
        // ================= M-block: msg[row, :] =================
        const int row = blk;
        if (tid < CH) basis_col<CH>(x[row * CH + tid], sm.mBt, tid);
        __syncthreads();

        // lane owns half-channels: c1=lane>>1 (g 0-3 or 4-7), c2=c1+32
        const int c1 = lane >> 1, c2 = c1 + 32, gs = (lane & 1) * 4;
        float B1[4], B2[4];
#pragma unroll
        for (int k = 0; k < 4; ++k) {
            B1[k] = sm.mBt[gs + k][c1];
            B2[k] = sm.mBt[gs + k][c2];
        }
        float sil1 = sm.mBt[8][c1], sil2 = sm.mBt[8][c2];
        float bflag = (lane & 1) ? 0.0f : 1.0f;   // base term counted once/ch

        float outv = 0.0f;
#pragma unroll 4
        for (int oi = 0; oi < 16; ++oi) {
            int o = w * 16 + oi;
            const float4* wp = (const float4*)(mws + o * CH * GK);
            float4 wA = wp[lane];        // 1KB contiguous: channels 0..31
            float4 wB = wp[64 + lane];   // 1KB contiguous: channels 32..63
            float scA = mwsc[o * CH + c1], scB = mwsc[o * CH + c2];
            float bwA = mwb[o * CH + c1], bwB = mwb[o * CH + c2];
            float val = (B1[0]*wA.x + B1[1]*wA.y + B1[2]*wA.z + B1[3]*wA.w) * scA
                      + (B2[0]*wB.x + B2[1]*wB.y + B2[2]*wB.z + B2[3]*wB.w) * scB
                      + (sil1 * bwA + sil2 * bwB) * bflag;
#pragma unroll
            for (int off = 32; off > 0; off >>= 1)
                val += __shfl_xor(val, off, 64);
            if (lane == oi) outv = val;
        }
        if (lane < 16) ws[WS_MSG + row * OUTF + w * 16 + lane] = outv;
        return;
    }

    // ================= E-block: energy quarter-row =================
    const int eb = blk - 512;
    const int b = eb >> 10, rem = eb & 1023, i = rem >> 2, jt = rem & 3;

    // stage x[b, jt*64..+64, :] (16 KB, contiguous reads) into tile[c][j]
    {
        const float* xb = x + (b * NB + jt * 64) * CH;
#pragma unroll
        for (int k = 0; k < 4; ++k) {
            int f = k * 1024 + tid * 4;          // contiguous 4KB per k
            float4 v = *(const float4*)(xb + f);
            int j = f >> 6, c = f & 63;          // 4 consecutive c's
            sm.e.tile[c + 0][j] = v.x;
            sm.e.tile[c + 1][j] = v.y;
            sm.e.tile[c + 2][j] = v.z;
            sm.e.tile[c + 3][j] = v.w;
        }
    }
    // cpad: per-interval cubic coefs (d=11 row stays zero)
#pragma unroll
    for (int ee = tid; ee < CH * 12; ee += 256) {
        int c = ee / 12, dd = ee - c * 12;
        float4 cf = make_float4(0.f, 0.f, 0.f, 0.f);
        if (dd <= 10) {
            float sc = fwsc[c];
            float w0 = 0.f, w1 = 0.f, w2 = 0.f, w3 = 0.f;
            int m0 = dd - 3;
            if ((unsigned)(m0 + 0) < 8u) w0 = fws[c * GK + m0 + 0] * sc;
            if ((unsigned)(m0 + 1) < 8u) w1 = fws[c * GK + m0 + 1] * sc;
            if ((unsigned)(m0 + 2) < 8u) w2 = fws[c * GK + m0 + 2] * sc;
            if ((unsigned)(m0 + 3) < 8u) w3 = fws[c * GK + m0 + 3] * sc;
            cf.x = (w0 + 4.0f * w1 + w2) * (1.0f / 6.0f);
            cf.y = (w2 - w0) * 0.5f;
            cf.z = (w0 - 2.0f * w1 + w2) * 0.5f;
            cf.w = (w3 - w0 + 3.0f * (w1 - w2)) * (1.0f / 6.0f);
        }
        sm.e.cpad[c][dd] = cf;
    }
    if (tid < CH)
        sm.e.xisf[tid] = make_float2(x[(b * NB + i) * CH + tid], fwb[tid]);
    __syncthreads();

    // wave w covers channels w*16..+15 for j = lane
    const int j = lane, c0 = w * 16;
    float e = 0.0f;
#pragma unroll
    for (int cc = 0; cc < 16; ++cc) {
        int c = c0 + cc;
        float xj = sm.e.tile[c][j];            // conflict-free (c uniform)
        float2 xs = sm.e.xisf[c];              // broadcast
        float r = xs.x - xj;
        float pp = (r + 2.2f) * 2.5f;
        float fd = floorf(pp);
        int d = (int)fd;
        float u = pp - fd;
        if ((unsigned)d > 10u) d = 11;
        float4 cf = sm.e.cpad[c][d];           // b128 gather (measured free)
        e += cf.x + u * (cf.y + u * (cf.z + u * cf.w)) + silu(r) * xs.y;
    }
    sm.e.part[w][j] = e;
    __syncthreads();

    if (tid < 64) {                            // wave 0: finish 64 j's
        float et = sm.e.part[0][tid] + sm.e.part[1][tid]
                 + sm.e.part[2][tid] + sm.e.part[3][tid];
        int av = adj[(b * NB + i) * NB + jt * 64 + tid];
        float pe = av ? __expf(et) : 0.0f;     // no max-sub: |e| small (R5/R6 ok)
        ws[WS_PEXP + (b * NB + i) * NB + jt * 64 + tid] = pe;
        float sw = pe;
#pragma unroll
        for (int off = 32; off > 0; off >>= 1)
            sw += __shfl_xor(sw, off, 64);
        if (tid == 0) ws[WS_PSUM + ((b * NB + i) << 2) + jt] = sw;
    }
}

// K2: one block per (b,i): denom -> aggregate -> update KAN -> out
__global__ __launch_bounds__(256, 4) void k2_kernel(
    const float* __restrict__ x,
    const float* __restrict__ uwb, const float* __restrict__ uws,
    const float* __restrict__ uwsc,
    const float* __restrict__ ws, float* __restrict__ out) {
    const int b = blockIdx.x >> 8, i = blockIdx.x & 255;
    const int tid = threadIdx.x, lane = tid & 63, w = tid >> 6;

    __shared__ float p[NB];
    __shared__ float Bt[9][UIN];
    __shared__ float part[4][OUTF];

    p[tid] = ws[WS_PEXP + (b * NB + i) * NB + tid];
    if (tid < CH)
        basis_col<UIN>(x[(b * NB + i) * CH + tid], Bt, tid);
    const float* ps = ws + WS_PSUM + ((b * NB + i) << 2);
    float rden = __builtin_amdgcn_rcpf(ps[0] + ps[1] + ps[2] + ps[3]);
    __syncthreads();

    // aggregate: thread (o=lane, seg=w), coalesced msg reads
    {
        const float* msgb = ws + WS_MSG + (b * NB + w * 64) * OUTF + lane;
        float a = 0.0f;
#pragma unroll 8
        for (int jj = 0; jj < 64; ++jj)
            a += p[w * 64 + jj] * msgb[jj * OUTF];
        part[w][lane] = a;
    }
    __syncthreads();
    if (tid < OUTF) {
        float ag = (part[0][tid] + part[1][tid] + part[2][tid] + part[3][tid])
                 * rden;
        basis_col<UIN>(ag, Bt, CH + tid);
    }
    __syncthreads();

    // update matvec: lane owns half-channels c1, c1+32, c1+64, c1+96
    const int c1 = lane >> 1, gs = (lane & 1) * 4;
    float B1[4], B2[4], B3[4], B4[4];
#pragma unroll
    for (int k = 0; k < 4; ++k) {
        B1[k] = Bt[gs + k][c1];
        B2[k] = Bt[gs + k][c1 + 32];
        B3[k] = Bt[gs + k][c1 + 64];
        B4[k] = Bt[gs + k][c1 + 96];
    }
    float s1 = Bt[8][c1], s2 = Bt[8][c1 + 32];
    float s3 = Bt[8][c1 + 64], s4 = Bt[8][c1 + 96];
    float bflag = (lane & 1) ? 0.0f : 1.0f;

    float outv = 0.0f;
#pragma unroll 2
    for (int oi = 0; oi < 16; ++oi) {
        int o = w * 16 + oi;
        const float4* wp = (const float4*)(uws + o * UIN * GK);
        float4 w1 = wp[lane];          // 1KB contiguous: ch 0..31
        float4 w2 = wp[64 + lane];     // ch 32..63
        float4 w3 = wp[128 + lane];    // ch 64..95
        float4 w4 = wp[192 + lane];    // ch 96..127
        const float* scp = uwsc + o * UIN;
        const float* bwp = uwb + o * UIN;
        float val = (B1[0]*w1.x + B1[1]*w1.y + B1[2]*w1.z + B1[3]*w1.w) * scp[c1]
                  + (B2[0]*w2.x + B2[1]*w2.y + B2[2]*w2.z + B2[3]*w2.w) * scp[c1 + 32]
                  + (B3[0]*w3.x + B3[1]*w3.y + B3[2]*w3.z + B3[3]*w3.w) * scp[c1 + 64]
                  + (B4[0]*w4.x + B4[1]*w4.y + B4[2]*w4.z + B4[3]*w4.w) * scp[c1 + 96]
                  + (s1 * bwp[c1] + s2 * bwp[c1 + 32]
                   + s3 * bwp[c1 + 64] + s4 * bwp[c1 + 96]) * bflag;
#pragma unroll
        for (int off = 32; off > 0; off >>= 1)
            val += __shfl_xor(val, off, 64);
        if (lane == oi) outv = val;
    }
    if (lane < 16) out[(b * NB + i) * OUTF + w * 16 + lane] = outv;
}

extern "C" void kernel_launch(void* const* d_in, const int* in_sizes, int n_in,
                              void* d_out, int out_size, void* d_ws, size_t ws_size,
                              hipStream_t stream) {
    const float* x     = (const float*)d_in[0];
    const int*   adj   = (const int*)d_in[1];
    const float* fwb   = (const float*)d_in[2];
    const float* fws   = (const float*)d_in[3];
    const float* fwsc  = (const float*)d_in[4];
    const float* mwb   = (const float*)d_in[5];
    const float* mws   = (const float*)d_in[6];
    const float* mwsc  = (const float*)d_in[7];
    const float* uwb   = (const float*)d_in[8];
    const float* uws   = (const float*)d_in[9];
    const float* uwsc  = (const float*)d_in[10];
    float* out = (float*)d_out;
    float* ws = (float*)d_ws;

    k1_kernel<<<2560, 256, 0, stream>>>(x, adj, fwb, fws, fwsc,
                                        mwb, mws, mwsc, ws);
    k2_kernel<<<512, 256, 0, stream>>>(x, uwb, uws, uwsc, ws, out);
}